// Round 15
// baseline (651.483 us; speedup 1.0000x reference)
//
#include <hip/hip_runtime.h>
#include <hip/hip_fp16.h>
#include <math.h>

#define NN   20000
#define EE   320000
#define RR   4
#define NBKT 4
#define BKTW 5000

typedef unsigned short u16;
typedef unsigned int   u32;
typedef _Float16 half8v __attribute__((ext_vector_type(8)));
typedef _Float16 v2h    __attribute__((ext_vector_type(2)));
typedef __attribute__((ext_vector_type(4))) float f32x4;

static __device__ __forceinline__ u16 f2h(float f){ return __half_as_ushort(__float2half_rn(f)); }
static __device__ __forceinline__ v2h u2v(u32 u){ union{u32 u; v2h v;} c; c.u=u; return c.v; }
static __device__ __forceinline__ u32 v2u(v2h v){ union{u32 u; v2h v;} c; c.v=v; return c.u; }
static __device__ __forceinline__ v2h splat2(float f){ v2h r; r[0]=(_Float16)f; r[1]=(_Float16)f; return r; }
static __device__ __forceinline__ float fdot2(v2h a, v2h b, float c){
  return __builtin_amdgcn_fdot2(a, b, c, false);
}
static __device__ __forceinline__ void gload_lds16(const void* g, void* l){
  __builtin_amdgcn_global_load_lds((const __attribute__((address_space(1))) void*)g,
                                   (__attribute__((address_space(3))) void*)l, 16, 0, 0);
}

// ---------------- CSR build (src-bucketed: each node's list ordered by src/5000) ----------------
// Buckets give gather temporal locality: resident waves process bucket b edges at roughly the
// same time, so each XCD's gather set is ~2.56 MB (one src bucket) instead of 10.2 MB.
__global__ void k_countA(const int* __restrict__ ei, int* __restrict__ degb){
  int i = blockIdx.x*blockDim.x + threadIdx.x;
  if (i < RR*EE) {
    int r = i / EE, e = i % EE;
    int s = ei[(size_t)r*2*EE + e];
    int d = ei[(size_t)r*2*EE + EE + e];
    int b = s / BKTW;
    atomicAdd(&degb[((size_t)r*NN + d)*NBKT + b], 1);
  }
}
__global__ __launch_bounds__(1024) void k_scan(const int* __restrict__ cnt_all, int* __restrict__ off_all,
                                               int* __restrict__ cur_all, int n){
  const int* cnt = cnt_all + (size_t)blockIdx.x*n;
  int* off = off_all + (size_t)blockIdx.x*(n+1);
  int* cur = cur_all + (size_t)blockIdx.x*n;
  __shared__ int part[1024];
  int t = threadIdx.x;
  int chunk = (n + 1023) >> 10;
  int lo = t*chunk; if (lo > n) lo = n;
  int hi = lo + chunk; if (hi > n) hi = n;
  int s = 0;
  for (int i = lo; i < hi; ++i) s += cnt[i];
  part[t] = s;
  __syncthreads();
  for (int d = 1; d < 1024; d <<= 1) {
    int u = (t >= d) ? part[t-d] : 0;
    __syncthreads();
    part[t] += u;
    __syncthreads();
  }
  int run = (t == 0) ? 0 : part[t-1];
  for (int i = lo; i < hi; ++i) { off[i] = run; cur[i] = run; run += cnt[i]; }
  if (t == 1023) off[n] = part[1023];
}
// merged scatter: pass = blockIdx.x/5000 (dst-range passes keep the random 4B writes L2-local).
// csr stores BYTE offset of the source row in XLR: src*4096 (2048 f16 elems * 2B).
__global__ void k_scatterM(const int* __restrict__ ei, int* __restrict__ curb, u32* __restrict__ csr4){
  int bid = blockIdx.x;
  int pass = bid / 5000;
  int i = (bid - pass*5000)*256 + threadIdx.x;
  int dlo = pass*5000, dhi = dlo + 5000;
  if (i < RR*EE) {
    int r = i / EE, e = i - r*EE;
    int d = ei[(size_t)r*2*EE + EE + e];
    if (d >= dlo && d < dhi) {
      int s = ei[(size_t)r*2*EE + e];
      int b = s / BKTW;
      int p = atomicAdd(&curb[((size_t)r*NN + d)*NBKT + b], 1);
      csr4[(size_t)r*EE + p] = (u32)s * 4096u;
    }
  }
}

// ---------------- fused prep: cast + 4 weight transposes + degb zero ----------------
static __device__ __forceinline__ void prep_body(const float* A, const float* B, u16* dst,
                                                 int K, int N, int total, int i){
  if (i >= total) return;
  int k = i % K;
  int n = (i / K) % (2*N);
  int r = i / (K*2*N);
  const float* S = (n < N) ? A : B;
  int nn = (n < N) ? n : n - N;
  dst[i] = f2h(S[((size_t)r*K + k)*N + nn]);
}
__global__ void k_prepall(const float* __restrict__ x, u16* __restrict__ xbf,
                          const float* __restrict__ Wl1, const float* __restrict__ Wr1, u16* __restrict__ W1T,
                          const float* __restrict__ Wl2, const float* __restrict__ Wr2, u16* __restrict__ W2T,
                          const float* __restrict__ W3a, const float* __restrict__ W3b, u16* __restrict__ W3T,
                          const float* __restrict__ W4a, const float* __restrict__ W4b, u16* __restrict__ W4T,
                          int* __restrict__ degb){
  int kind = blockIdx.y;
  int i = blockIdx.x*256 + threadIdx.x;
  if (kind == 0) {                                  // x f32 -> f16, float4-wide
    if (i < NN*256/4) {
      float4 v = reinterpret_cast<const float4*>(x)[i];
      ushort4 b;
      b.x = f2h(v.x); b.y = f2h(v.y); b.z = f2h(v.z); b.w = f2h(v.w);
      reinterpret_cast<ushort4*>(xbf)[i] = b;
    }
  } else if (kind == 1) prep_body(Wl1, Wr1, W1T, 256, 256, RR*512*256, i);
  else if (kind == 2)   prep_body(Wl2, Wr2, W2T, 256, 256, RR*512*256, i);
  else if (kind == 3)   prep_body(W3a, W3b, W3T, 256, 64,  RR*128*256, i);
  else if (kind == 4)   prep_body(W4a, W4b, W4T, 64,  64,  RR*128*64,  i);
  else { if (i < RR*NN*NBKT) degb[i] = 0; }
}

// ---------------- MFMA GEMM (f16): Cb = A@BT^T; XCD-chunked 1-D grid ----------------
// bid%8 = XCD; each XCD owns a contiguous bx chunk and iterates all (by,z) within it,
// so concurrent blocks on one XCD share an A-window (~256KB) + B tiles (~1MB) in its L2.
__global__ __launch_bounds__(256) void k_mfma(
    const u16* __restrict__ A, const u16* __restrict__ BT,
    int M, int K, u16* __restrict__ Cb, int ldc,
    long aZ, long btZ, long cZ, int nby, int nz)
{
  constexpr int BM = 128, BN = 128;
  constexpr int FI = 4, FJ = 4;
  constexpr int CH = 20;                 // bx chunk per XCD (8*20*128 >= 20000)
  const int bid = blockIdx.x;
  const int xcd = bid & 7;
  const int u   = bid >> 3;
  const int nbz = nby*nz;
  const int byz = u % nbz;
  const int bxi = u / nbz;
  const int bx  = xcd*CH + bxi;
  const int bm  = bx * BM;
  if (bm >= M) return;
  const int by  = byz % nby;
  const int zz  = byz / nby;
  const int bn  = by * BN;
  A  += (size_t)zz*aZ;
  BT += (size_t)zz*btZ;
  Cb += (size_t)zz*cZ;

  __shared__ u16 As[BM*32];
  __shared__ u16 Bs[BN*32];
  const int t = threadIdx.x;
  const int lane = t & 63, wid = t >> 6;
  const int wr = wid >> 1, wc = wid & 1;
  const int lr = lane & 15, lk = lane >> 4;

  f32x4 acc[FI][FJ];
  #pragma unroll
  for (int i = 0; i < FI; ++i)
    #pragma unroll
    for (int j = 0; j < FJ; ++j) acc[i][j] = (f32x4)(0.f);

  const int nk = K >> 5;
  char* AsB = (char*)As;
  char* BsB = (char*)Bs;

  for (int s = 0; s < nk; ++s) {
    const int kk = s << 5;
    #pragma unroll
    for (int i = 0; i < 2; ++i) {
      int c = t + 256*i;
      int row = c >> 2, sub = c & 3;
      int lsub = sub ^ (row & 3);
      int grow = bm + row; if (grow >= M) grow = M - 1;
      gload_lds16(A + (size_t)grow*K + kk + lsub*8, AsB + c*16);
    }
    #pragma unroll
    for (int i = 0; i < 2; ++i) {
      int c = t + 256*i;
      int row = c >> 2, sub = c & 3;
      int lsub = sub ^ (row & 3);
      gload_lds16(BT + (size_t)(bn + row)*K + kk + lsub*8, BsB + c*16);
    }
    __syncthreads();
    half8v a[FI], b[FJ];
    #pragma unroll
    for (int i = 0; i < FI; ++i) {
      int row = wr*64 + i*16 + lr;
      int sub = lk ^ (row & 3);
      a[i] = *reinterpret_cast<half8v*>(AsB + row*64 + sub*16);
    }
    #pragma unroll
    for (int j = 0; j < FJ; ++j) {
      int col = wc*64 + j*16 + lr;
      int sub = lk ^ (col & 3);
      b[j] = *reinterpret_cast<half8v*>(BsB + col*64 + sub*16);
    }
    #pragma unroll
    for (int i = 0; i < FI; ++i)
      #pragma unroll
      for (int j = 0; j < FJ; ++j)
        acc[i][j] = __builtin_amdgcn_mfma_f32_16x16x32_f16(a[i], b[j], acc[i][j], 0, 0, 0);
    __syncthreads();
  }

  #pragma unroll
  for (int i = 0; i < FI; ++i) {
    #pragma unroll
    for (int j = 0; j < FJ; ++j) {
      int col = bn + wc*64 + j*16 + lr;
      #pragma unroll
      for (int q = 0; q < 4; ++q) {
        int row = bm + wr*64 + i*16 + lk*4 + q;
        if (row < M) Cb[(size_t)row*ldc + col] = f2h(acc[i][j][q]);
      }
    }
  }
}

// ---------------- GATv2 attention: XCD-relation affinity, src-bucketed lists ----------------
// 1-D grid of 20000 blocks; blocks with bid%8 in {2z,2z+1} serve relation z (XCD pair).
// offb is bucketed: e0 = offb[node*4], e1 = offb[node*4+4] (list ordered by src bucket).
// xlr [NN][2048]: relation z at cols z*512.. (0-255 xl, 256-511 xr). csr holds src*4096 byte offsets.
// Weight scaling: w = exp2(p - 6) (power-of-2 scale cancels in a/s; cap 2^12 guards overflow).
__global__ __launch_bounds__(256) void k_gat(
    const u16* __restrict__ xlr,
    const float* __restrict__ att, const float* __restrict__ bias,
    const int* __restrict__ offb4, const u32* __restrict__ csr4,
    u16* __restrict__ out)
{
  const int bid = blockIdx.x;
  const int z = (bid & 7) >> 1;                       // XCD pair -> relation
  const int j4 = ((bid >> 3) << 1) | (bid & 1);       // 0..4999 within relation
  const int node = j4*4 + (threadIdx.x >> 6);
  if (node >= NN) return;
  const int lane = threadIdx.x & 63;
  const int sl = lane & 31, sub = lane >> 5;
  const int* offb = offb4 + (size_t)z*(NBKT*NN+1);
  const u32* csr = csr4 + (size_t)z*EE;
  u16* outp = out + (size_t)z*(size_t)NN*256;

  const int co = sl*8;
  const char* xc = (const char*)xlr + (size_t)z*1024 + co*2;  // lane's channel base in z-slice
  const u16* selfrow = xlr + (size_t)z*512 + (size_t)node*2048;
  const v2h c02 = splat2(0.2f);
  const float L2E = 1.4426950408889634f;

  uint4 rx = *reinterpret_cast<const uint4*>(selfrow + 256 + co);
  v2h xr2[4] = {u2v(rx.x), u2v(rx.y), u2v(rx.z), u2v(rx.w)};
  v2h av2[4];
  {
    float4 q0 = *reinterpret_cast<const float4*>(att + z*256 + co);
    float4 q1 = *reinterpret_cast<const float4*>(att + z*256 + co + 4);
    av2[0][0]=(_Float16)(q0.x*L2E); av2[0][1]=(_Float16)(q0.y*L2E);
    av2[1][0]=(_Float16)(q0.z*L2E); av2[1][1]=(_Float16)(q0.w*L2E);
    av2[2][0]=(_Float16)(q1.x*L2E); av2[2][1]=(_Float16)(q1.y*L2E);
    av2[3][0]=(_Float16)(q1.z*L2E); av2[3][1]=(_Float16)(q1.w*L2E);
  }
  // self loop (sub 0 only)
  uint4 sx = *reinterpret_cast<const uint4*>(selfrow + co);
  v2h xs2[4] = {u2v(sx.x), u2v(sx.y), u2v(sx.z), u2v(sx.w)};
  float ps = 0.f;
  #pragma unroll
  for (int i = 0; i < 4; ++i) {
    v2h zz = xs2[i] + xr2[i];
    v2h lr = __builtin_elementwise_max(zz, zz*c02);
    ps = fdot2(av2[i], lr, ps);
  }
  ps += __shfl_xor(ps,1); ps += __shfl_xor(ps,2); ps += __shfl_xor(ps,4);
  float wsf = (sub == 0) ? exp2f(fminf(ps - 6.f, 12.f)) : 0.f;
  float s = wsf;
  v2h a2[4];
  {
    v2h w2 = splat2(wsf);
    #pragma unroll
    for (int i = 0; i < 4; ++i) a2[i] = w2*xs2[i];
  }

  const int e0 = offb[node*NBKT], e1 = offb[node*NBKT + NBKT];
  const int kfull = e0 + ((e1 - e0) & ~7);
  // main loop: full 8-edge chunks, NO predication (all indices valid)
  for (int k = e0; k < kfull; k += 8) {
    v2h xv[4][4];
    float p[4];
    #pragma unroll
    for (int j = 0; j < 4; ++j) {
      u32 boff = csr[k + 2*j + sub];
      uint4 v = *reinterpret_cast<const uint4*>(xc + boff);
      xv[j][0]=u2v(v.x); xv[j][1]=u2v(v.y); xv[j][2]=u2v(v.z); xv[j][3]=u2v(v.w);
      float pp = 0.f;
      #pragma unroll
      for (int i = 0; i < 4; ++i) {
        v2h zz = xv[j][i] + xr2[i];
        v2h lr = __builtin_elementwise_max(zz, zz*c02);
        pp = fdot2(av2[i], lr, pp);
      }
      p[j] = pp;
    }
    #pragma unroll
    for (int j = 0; j < 4; ++j) {
      p[j] += __shfl_xor(p[j],1);
      p[j] += __shfl_xor(p[j],2);
      p[j] += __shfl_xor(p[j],4);
    }
    float w[4];
    #pragma unroll
    for (int j = 0; j < 4; ++j) w[j] = exp2f(fminf(p[j] - 6.f, 12.f));
    s += (w[0] + w[1]) + (w[2] + w[3]);
    #pragma unroll
    for (int j = 0; j < 4; ++j) {
      v2h w2 = splat2(w[j]);
      #pragma unroll
      for (int i = 0; i < 4; ++i) a2[i] += w2*xv[j][i];
    }
  }
  // tail: up to 7 edges, 2 per iter (1 per sub-half), predicated
  for (int k = kfull; k < e1; k += 2) {
    int kk = k + sub;
    bool val = kk < e1;
    u32 boff = csr[val ? kk : e1-1];
    uint4 v = *reinterpret_cast<const uint4*>(xc + boff);
    v2h xv[4] = {u2v(v.x), u2v(v.y), u2v(v.z), u2v(v.w)};
    float pp = 0.f;
    #pragma unroll
    for (int i = 0; i < 4; ++i) {
      v2h zz = xv[i] + xr2[i];
      v2h lr = __builtin_elementwise_max(zz, zz*c02);
      pp = fdot2(av2[i], lr, pp);
    }
    pp += __shfl_xor(pp,1); pp += __shfl_xor(pp,2); pp += __shfl_xor(pp,4);
    float w = val ? exp2f(fminf(pp - 6.f, 12.f)) : 0.f;
    s += w;
    v2h w2 = splat2(w);
    #pragma unroll
    for (int i = 0; i < 4; ++i) a2[i] += w2*xv[i];
  }
  // combine sub-halves
  s += __shfl_xor(s, 32);
  #pragma unroll
  for (int i = 0; i < 4; ++i) {
    u32 t = (u32)__shfl_xor((int)v2u(a2[i]), 32);
    a2[i] += u2v(t);
  }
  float inv = 1.f / s;
  if (sub == 0) {
    float4 b0 = *reinterpret_cast<const float4*>(bias + z*256 + co);
    float4 b1 = *reinterpret_cast<const float4*>(bias + z*256 + co + 4);
    float bv[8] = {b0.x,b0.y,b0.z,b0.w,b1.x,b1.y,b1.z,b1.w};
    u32 o[4];
    #pragma unroll
    for (int i = 0; i < 4; ++i) {
      float lo = fmaxf((float)a2[i][0]*inv + bv[2*i],   0.f);
      float hi = fmaxf((float)a2[i][1]*inv + bv[2*i+1], 0.f);
      o[i] = (u32)f2h(lo) | ((u32)f2h(hi) << 16);
    }
    uint4 ov = {o[0], o[1], o[2], o[3]};
    *reinterpret_cast<uint4*>(outp + (size_t)node*256 + co) = ov;
  }
}

// ---------------- GraphConv: aggregate projected P-slice; XCD-relation affinity ----------------
// C [R][NN][128] f16 = [P|Q]; result = act(sum_j P[j] + Q[i] + bias).
// csr byte offsets are src*4096; C-row byte offset = src*256 = boff>>4. Bucketed offsets.
template<int RELU, int F32OUT>
__global__ __launch_bounds__(256) void k_aggp(
    const u16* __restrict__ C, const float* __restrict__ bias,
    const int* __restrict__ offb4, const u32* __restrict__ csr4,
    u16* __restrict__ outb, float* __restrict__ outf)
{
  const int bid = blockIdx.x;
  const int z = (bid & 7) >> 1;
  const int j4 = ((bid >> 3) << 1) | (bid & 1);
  const int node = j4*4 + (threadIdx.x >> 6);
  if (node >= NN) return;
  const int lane = threadIdx.x & 63;
  const int g = lane >> 4, sl = lane & 15;
  const u16* Cp = C + (size_t)z*(size_t)NN*128;
  const char* Cc = (const char*)Cp + sl*8;   // 4 channels (8B) per lane
  const int* offb = offb4 + (size_t)z*(NBKT*NN+1);
  const u32* csr = csr4 + (size_t)z*EE;
  const int co = sl*4;
  v2h acc0 = splat2(0.f), acc1 = splat2(0.f);
  const int e0 = offb[node*NBKT], e1 = offb[node*NBKT + NBKT];
  const int kfull = e0 + ((e1 - e0) & ~7);
  for (int k = e0; k < kfull; k += 8) {      // 2 edges per 16-lane group, unpredicated
    #pragma unroll
    for (int j = 0; j < 2; ++j) {
      u32 boff = csr[k + 2*g + j] >> 4;
      uint2 v = *reinterpret_cast<const uint2*>(Cc + boff);
      acc0 += u2v(v.x);
      acc1 += u2v(v.y);
    }
  }
  for (int k = kfull; k < e1; k += 4) {      // tail: 1 edge per group, predicated
    int kk = k + g;
    bool val = kk < e1;
    u32 boff = csr[val ? kk : e1-1] >> 4;
    uint2 v = *reinterpret_cast<const uint2*>(Cc + boff);
    acc0 += u2v(val ? v.x : 0u);
    acc1 += u2v(val ? v.y : 0u);
  }
  // cross-group reduce in f32
  float a0 = (float)acc0[0], a1 = (float)acc0[1];
  float a2 = (float)acc1[0], a3 = (float)acc1[1];
  a0 += __shfl_xor(a0,16); a1 += __shfl_xor(a1,16);
  a2 += __shfl_xor(a2,16); a3 += __shfl_xor(a3,16);
  a0 += __shfl_xor(a0,32); a1 += __shfl_xor(a1,32);
  a2 += __shfl_xor(a2,32); a3 += __shfl_xor(a3,32);
  if (g == 0) {
    uint2 q = *reinterpret_cast<const uint2*>(Cp + (size_t)node*128 + 64 + co);
    v2h q0 = u2v(q.x), q1 = u2v(q.y);
    float4 bv = *reinterpret_cast<const float4*>(bias + z*64 + co);
    float v0 = a0 + (float)q0[0] + bv.x;
    float v1 = a1 + (float)q0[1] + bv.y;
    float v2 = a2 + (float)q1[0] + bv.z;
    float v3 = a3 + (float)q1[1] + bv.w;
    if (RELU) {
      v0 = fmaxf(v0, 0.f); v1 = fmaxf(v1, 0.f);
      v2 = fmaxf(v2, 0.f); v3 = fmaxf(v3, 0.f);
    }
    if (F32OUT) {
      float4 o = {v0, v1, v2, v3};
      *reinterpret_cast<float4*>(outf + (size_t)node*256 + z*64 + co) = o;
    } else {
      uint2 o;
      o.x = (u32)f2h(v0) | ((u32)f2h(v1) << 16);
      o.y = (u32)f2h(v2) | ((u32)f2h(v3) << 16);
      *reinterpret_cast<uint2*>(outb + ((size_t)z*NN + node)*64 + co) = o;
    }
  }
}

// ---------------- orchestration ----------------
extern "C" void kernel_launch(void* const* d_in, const int* in_sizes, int n_in,
                              void* d_out, int out_size, void* d_ws, size_t ws_size,
                              hipStream_t stream)
{
  const float* x      = (const float*)d_in[0];
  const int*   ei     = (const int*)  d_in[1];
  const float* Wl1    = (const float*)d_in[2];
  const float* Wr1    = (const float*)d_in[3];
  const float* att1   = (const float*)d_in[4];
  const float* b1     = (const float*)d_in[5];
  const float* Wl2    = (const float*)d_in[6];
  const float* Wr2    = (const float*)d_in[7];
  const float* att2   = (const float*)d_in[8];
  const float* b2     = (const float*)d_in[9];
  const float* Wrel3  = (const float*)d_in[10];
  const float* Wroot3 = (const float*)d_in[11];
  const float* b3     = (const float*)d_in[12];
  const float* Wrel4  = (const float*)d_in[13];
  const float* Wroot4 = (const float*)d_in[14];
  const float* b4     = (const float*)d_in[15];
  float* out = (float*)d_out;

  const dim3 thr(256);
  const size_t NB2048 = (size_t)NN*2048;
  const size_t NB256  = (size_t)NN*256;
  const size_t NB128  = (size_t)NN*128;
  const size_t NB64   = (size_t)NN*64;

  u16* XLR = (u16*)d_ws;                          // [NN][2048] (all relations side by side)
  u16* h   = XLR + NB2048;                        // [R][NN][256]
  u16* xbf = h   + NB256*RR;                      // [NN][256]
  u16* W1T = xbf + NB256;                         // [2048][256] (= [R][512][256])
  u16* W2T = W1T + (size_t)RR*512*256;
  u16* W3T = W2T + (size_t)RR*512*256;            // [R][128][256]
  u16* W4T = W3T + (size_t)RR*128*256;            // [R][128][64]
  int* degb = (int*)(W4T + (size_t)RR*128*64);    // [R][NN][4]
  int* offb = degb + (size_t)RR*NN*NBKT;          // R*(4NN+1)
  int* curb = offb + (size_t)RR*(NBKT*NN+1);      // [R][NN][4]
  u32* csr4 = (u32*)(curb + (size_t)RR*NN*NBKT);  // R*EE (byte offsets)
  u16* C34 = XLR;                                 // [R][NN][128] aliases XLR
  u16* h3b = XLR + NB128*RR;                      // [R][NN][64]  aliases XLR (disjoint)

  // fused prep: kind 0 = cast x, kinds 1-4 = weight transposes, kind 5 = zero degb
  k_prepall<<<dim3(5000,6), thr, 0, stream>>>(x, xbf, Wl1, Wr1, W1T, Wl2, Wr2, W2T,
                                              Wrel3, Wroot3, W3T, Wrel4, Wroot4, W4T, degb);

  // CSR (src-bucketed)
  k_countA  <<<dim3((RR*EE+255)/256), thr, 0, stream>>>(ei, degb);
  k_scan    <<<dim3(RR), dim3(1024), 0, stream>>>(degb, offb, curb, NBKT*NN);
  k_scatterM<<<dim3(20000), thr, 0, stream>>>(ei, curb, csr4);

  const dim3 gNode(20000);                        // gat/aggp: XCD-pair relation affinity
  // L1: XLR = xbf @ W1T^T  (fused GEMM, N=2048; XCD-chunked 1-D grid)
  k_mfma<<<dim3(8*20*16), thr, 0, stream>>>(xbf, W1T, NN, 256, XLR, 2048, 0, 0, 0, 16, 1);
  k_gat<<<gNode, thr, 0, stream>>>(XLR, att1, b1, offb, csr4, h);
  // L2: per-z GEMM back into XLR column slices
  k_mfma<<<dim3(8*20*16), thr, 0, stream>>>(h, W2T, NN, 256, XLR, 2048,
                                            (long)NB256, 512*256, 512, 4, 4);
  k_gat<<<gNode, thr, 0, stream>>>(XLR, att2, b2, offb, csr4, h);
  // L3: C34[z] = h[z] @ [Wrel3|Wroot3][z] ; h3 = relu(aggP + Q + b3)
  k_mfma<<<dim3(8*20*4), thr, 0, stream>>>(h, W3T, NN, 256, C34, 128,
                                           (long)NB256, 128*256, (long)NB128, 1, 4);
  k_aggp<1,0><<<gNode, thr, 0, stream>>>(C34, b3, offb, csr4, h3b, nullptr);
  // L4: C34[z] = h3[z] @ [Wrel4|Wroot4][z] ; out[:,z,:] = aggP + Q + b4
  k_mfma<<<dim3(8*20*4), thr, 0, stream>>>(h3b, W4T, NN, 64, C34, 128,
                                           (long)NB64, 128*64, (long)NB128, 1, 4);
  k_aggp<0,1><<<gNode, thr, 0, stream>>>(C34, b4, offb, csr4, nullptr, out);
}

// Round 16
// 488.524 us; speedup vs baseline: 1.3336x; 1.3336x over previous
//
#include <hip/hip_runtime.h>
#include <hip/hip_fp16.h>
#include <math.h>

#define NN   20000
#define EE   320000
#define RR   4
#define NBKT 4
#define BKTW 5000
#define SM   (NBKT*NN)     // 80000 scan elements per relation
#define SB   40            // scan blocks per relation
#define SE   2000          // elements per scan block

typedef unsigned short u16;
typedef unsigned int   u32;
typedef _Float16 half8v __attribute__((ext_vector_type(8)));
typedef _Float16 v2h    __attribute__((ext_vector_type(2)));
typedef __attribute__((ext_vector_type(4))) float f32x4;

static __device__ __forceinline__ u16 f2h(float f){ return __half_as_ushort(__float2half_rn(f)); }
static __device__ __forceinline__ v2h u2v(u32 u){ union{u32 u; v2h v;} c; c.u=u; return c.v; }
static __device__ __forceinline__ u32 v2u(v2h v){ union{u32 u; v2h v;} c; c.v=v; return c.u; }
static __device__ __forceinline__ v2h splat2(float f){ v2h r; r[0]=(_Float16)f; r[1]=(_Float16)f; return r; }
static __device__ __forceinline__ float fdot2(v2h a, v2h b, float c){
  return __builtin_amdgcn_fdot2(a, b, c, false);
}
static __device__ __forceinline__ void gload_lds16(const void* g, void* l){
  __builtin_amdgcn_global_load_lds((const __attribute__((address_space(1))) void*)g,
                                   (__attribute__((address_space(3))) void*)l, 16, 0, 0);
}

// ---------------- CSR build (src-bucketed lists; parallel 3-phase scan) ----------------
__global__ void k_countA(const int* __restrict__ ei, int* __restrict__ degb){
  int i = blockIdx.x*blockDim.x + threadIdx.x;
  if (i < RR*EE) {
    int r = i / EE, e = i % EE;
    int s = ei[(size_t)r*2*EE + e];
    int d = ei[(size_t)r*2*EE + EE + e];
    int b = s / BKTW;
    atomicAdd(&degb[((size_t)r*NN + d)*NBKT + b], 1);
  }
}
// phase A: block sums (160 blocks x 2000 elements)
__global__ __launch_bounds__(256) void k_scanA(const int* __restrict__ degb, int* __restrict__ bsum){
  int r = blockIdx.x / SB, b = blockIdx.x % SB;
  const int* p = degb + (size_t)r*SM + b*SE;
  int t = threadIdx.x;
  int s = 0;
  for (int i = t; i < SE; i += 256) s += p[i];
  s += __shfl_xor(s,1); s += __shfl_xor(s,2); s += __shfl_xor(s,4);
  s += __shfl_xor(s,8); s += __shfl_xor(s,16); s += __shfl_xor(s,32);
  __shared__ int ws[4];
  if ((t & 63) == 0) ws[t >> 6] = s;
  __syncthreads();
  if (t == 0) bsum[blockIdx.x] = ws[0] + ws[1] + ws[2] + ws[3];
}
// phase B: scan the 40 block sums per relation (in-place -> exclusive bases); write total
__global__ void k_scanB(int* __restrict__ bsum, int* __restrict__ off_all){
  int r = blockIdx.x;
  if (threadIdx.x == 0) {
    int run = 0;
    for (int b = 0; b < SB; ++b) {
      int v = bsum[r*SB + b];
      bsum[r*SB + b] = run;
      run += v;
    }
    off_all[(size_t)r*(SM+1) + SM] = run;   // == EE
  }
}
// phase C: per-block exclusive scan + base -> off/cur (8 elems/thread, LDS block scan)
__global__ __launch_bounds__(256) void k_scanC(const int* __restrict__ degb, const int* __restrict__ bsum,
                                               int* __restrict__ off_all, int* __restrict__ cur_all){
  int r = blockIdx.x / SB, b = blockIdx.x % SB;
  const int* p = degb + (size_t)r*SM + b*SE;
  int* off = off_all + (size_t)r*(SM+1) + b*SE;
  int* cur = cur_all + (size_t)r*SM + b*SE;
  int t = threadIdx.x;
  int base_i = t*8;                       // threads 0..249 active (250*8 = 2000)
  int v[8]; int tot = 0;
  if (base_i < SE) {
    #pragma unroll
    for (int j = 0; j < 8; ++j) { v[j] = p[base_i + j]; tot += v[j]; }
  }
  __shared__ int part[256];
  part[t] = tot;
  __syncthreads();
  for (int d = 1; d < 256; d <<= 1) {
    int u = (t >= d) ? part[t-d] : 0;
    __syncthreads();
    part[t] += u;
    __syncthreads();
  }
  if (base_i < SE) {
    int run = bsum[r*SB + b] + ((t == 0) ? 0 : part[t-1]);
    #pragma unroll
    for (int j = 0; j < 8; ++j) {
      off[base_i + j] = run;
      cur[base_i + j] = run;
      run += v[j];
    }
  }
}
// merged scatter: pass = blockIdx.x/5000 (dst-range passes keep the random 4B writes L2-local).
// csr stores BYTE offset of the source row in XLR: src*4096 (2048 f16 elems * 2B).
__global__ void k_scatterM(const int* __restrict__ ei, int* __restrict__ curb, u32* __restrict__ csr4){
  int bid = blockIdx.x;
  int pass = bid / 5000;
  int i = (bid - pass*5000)*256 + threadIdx.x;
  int dlo = pass*5000, dhi = dlo + 5000;
  if (i < RR*EE) {
    int r = i / EE, e = i - r*EE;
    int d = ei[(size_t)r*2*EE + EE + e];
    if (d >= dlo && d < dhi) {
      int s = ei[(size_t)r*2*EE + e];
      int b = s / BKTW;
      int p = atomicAdd(&curb[((size_t)r*NN + d)*NBKT + b], 1);
      csr4[(size_t)r*EE + p] = (u32)s * 4096u;
    }
  }
}

// ---------------- fused prep: cast + 4 weight transposes + degb zero ----------------
static __device__ __forceinline__ void prep_body(const float* A, const float* B, u16* dst,
                                                 int K, int N, int total, int i){
  if (i >= total) return;
  int k = i % K;
  int n = (i / K) % (2*N);
  int r = i / (K*2*N);
  const float* S = (n < N) ? A : B;
  int nn = (n < N) ? n : n - N;
  dst[i] = f2h(S[((size_t)r*K + k)*N + nn]);
}
__global__ void k_prepall(const float* __restrict__ x, u16* __restrict__ xbf,
                          const float* __restrict__ Wl1, const float* __restrict__ Wr1, u16* __restrict__ W1T,
                          const float* __restrict__ Wl2, const float* __restrict__ Wr2, u16* __restrict__ W2T,
                          const float* __restrict__ W3a, const float* __restrict__ W3b, u16* __restrict__ W3T,
                          const float* __restrict__ W4a, const float* __restrict__ W4b, u16* __restrict__ W4T,
                          int* __restrict__ degb){
  int kind = blockIdx.y;
  int i = blockIdx.x*256 + threadIdx.x;
  if (kind == 0) {                                  // x f32 -> f16, float4-wide
    if (i < NN*256/4) {
      float4 v = reinterpret_cast<const float4*>(x)[i];
      ushort4 b;
      b.x = f2h(v.x); b.y = f2h(v.y); b.z = f2h(v.z); b.w = f2h(v.w);
      reinterpret_cast<ushort4*>(xbf)[i] = b;
    }
  } else if (kind == 1) prep_body(Wl1, Wr1, W1T, 256, 256, RR*512*256, i);
  else if (kind == 2)   prep_body(Wl2, Wr2, W2T, 256, 256, RR*512*256, i);
  else if (kind == 3)   prep_body(W3a, W3b, W3T, 256, 64,  RR*128*256, i);
  else if (kind == 4)   prep_body(W4a, W4b, W4T, 64,  64,  RR*128*64,  i);
  else { if (i < RR*NN*NBKT) degb[i] = 0; }
}

// ---------------- MFMA GEMM (f16): Cb = A@BT^T; XCD-chunked 1-D grid ----------------
__global__ __launch_bounds__(256) void k_mfma(
    const u16* __restrict__ A, const u16* __restrict__ BT,
    int M, int K, u16* __restrict__ Cb, int ldc,
    long aZ, long btZ, long cZ, int nby, int nz)
{
  constexpr int BM = 128, BN = 128;
  constexpr int FI = 4, FJ = 4;
  constexpr int CH = 20;                 // bx chunk per XCD (8*20*128 >= 20000)
  const int bid = blockIdx.x;
  const int xcd = bid & 7;
  const int u   = bid >> 3;
  const int nbz = nby*nz;
  const int byz = u % nbz;
  const int bxi = u / nbz;
  const int bx  = xcd*CH + bxi;
  const int bm  = bx * BM;
  if (bm >= M) return;
  const int by  = byz % nby;
  const int zz  = byz / nby;
  const int bn  = by * BN;
  A  += (size_t)zz*aZ;
  BT += (size_t)zz*btZ;
  Cb += (size_t)zz*cZ;

  __shared__ u16 As[BM*32];
  __shared__ u16 Bs[BN*32];
  const int t = threadIdx.x;
  const int lane = t & 63, wid = t >> 6;
  const int wr = wid >> 1, wc = wid & 1;
  const int lr = lane & 15, lk = lane >> 4;

  f32x4 acc[FI][FJ];
  #pragma unroll
  for (int i = 0; i < FI; ++i)
    #pragma unroll
    for (int j = 0; j < FJ; ++j) acc[i][j] = (f32x4)(0.f);

  const int nk = K >> 5;
  char* AsB = (char*)As;
  char* BsB = (char*)Bs;

  for (int s = 0; s < nk; ++s) {
    const int kk = s << 5;
    #pragma unroll
    for (int i = 0; i < 2; ++i) {
      int c = t + 256*i;
      int row = c >> 2, sub = c & 3;
      int lsub = sub ^ (row & 3);
      int grow = bm + row; if (grow >= M) grow = M - 1;
      gload_lds16(A + (size_t)grow*K + kk + lsub*8, AsB + c*16);
    }
    #pragma unroll
    for (int i = 0; i < 2; ++i) {
      int c = t + 256*i;
      int row = c >> 2, sub = c & 3;
      int lsub = sub ^ (row & 3);
      gload_lds16(BT + (size_t)(bn + row)*K + kk + lsub*8, BsB + c*16);
    }
    __syncthreads();
    half8v a[FI], b[FJ];
    #pragma unroll
    for (int i = 0; i < FI; ++i) {
      int row = wr*64 + i*16 + lr;
      int sub = lk ^ (row & 3);
      a[i] = *reinterpret_cast<half8v*>(AsB + row*64 + sub*16);
    }
    #pragma unroll
    for (int j = 0; j < FJ; ++j) {
      int col = wc*64 + j*16 + lr;
      int sub = lk ^ (col & 3);
      b[j] = *reinterpret_cast<half8v*>(BsB + col*64 + sub*16);
    }
    #pragma unroll
    for (int i = 0; i < FI; ++i)
      #pragma unroll
      for (int j = 0; j < FJ; ++j)
        acc[i][j] = __builtin_amdgcn_mfma_f32_16x16x32_f16(a[i], b[j], acc[i][j], 0, 0, 0);
    __syncthreads();
  }

  #pragma unroll
  for (int i = 0; i < FI; ++i) {
    #pragma unroll
    for (int j = 0; j < FJ; ++j) {
      int col = bn + wc*64 + j*16 + lr;
      #pragma unroll
      for (int q = 0; q < 4; ++q) {
        int row = bm + wr*64 + i*16 + lk*4 + q;
        if (row < M) Cb[(size_t)row*ldc + col] = f2h(acc[i][j][q]);
      }
    }
  }
}

// ---------------- GATv2 attention: XCD-relation affinity, src-bucketed lists ----------------
__global__ __launch_bounds__(256) void k_gat(
    const u16* __restrict__ xlr,
    const float* __restrict__ att, const float* __restrict__ bias,
    const int* __restrict__ offb4, const u32* __restrict__ csr4,
    u16* __restrict__ out)
{
  const int bid = blockIdx.x;
  const int z = (bid & 7) >> 1;                       // XCD pair -> relation
  const int j4 = ((bid >> 3) << 1) | (bid & 1);       // 0..4999 within relation
  const int node = j4*4 + (threadIdx.x >> 6);
  if (node >= NN) return;
  const int lane = threadIdx.x & 63;
  const int sl = lane & 31, sub = lane >> 5;
  const int* offb = offb4 + (size_t)z*(SM+1);
  const u32* csr = csr4 + (size_t)z*EE;
  u16* outp = out + (size_t)z*(size_t)NN*256;

  const int co = sl*8;
  const char* xc = (const char*)xlr + (size_t)z*1024 + co*2;  // lane's channel base in z-slice
  const u16* selfrow = xlr + (size_t)z*512 + (size_t)node*2048;
  const v2h c02 = splat2(0.2f);
  const float L2E = 1.4426950408889634f;

  uint4 rx = *reinterpret_cast<const uint4*>(selfrow + 256 + co);
  v2h xr2[4] = {u2v(rx.x), u2v(rx.y), u2v(rx.z), u2v(rx.w)};
  v2h av2[4];
  {
    float4 q0 = *reinterpret_cast<const float4*>(att + z*256 + co);
    float4 q1 = *reinterpret_cast<const float4*>(att + z*256 + co + 4);
    av2[0][0]=(_Float16)(q0.x*L2E); av2[0][1]=(_Float16)(q0.y*L2E);
    av2[1][0]=(_Float16)(q0.z*L2E); av2[1][1]=(_Float16)(q0.w*L2E);
    av2[2][0]=(_Float16)(q1.x*L2E); av2[2][1]=(_Float16)(q1.y*L2E);
    av2[3][0]=(_Float16)(q1.z*L2E); av2[3][1]=(_Float16)(q1.w*L2E);
  }
  // self loop (sub 0 only)
  uint4 sx = *reinterpret_cast<const uint4*>(selfrow + co);
  v2h xs2[4] = {u2v(sx.x), u2v(sx.y), u2v(sx.z), u2v(sx.w)};
  float ps = 0.f;
  #pragma unroll
  for (int i = 0; i < 4; ++i) {
    v2h zz = xs2[i] + xr2[i];
    v2h lr = __builtin_elementwise_max(zz, zz*c02);
    ps = fdot2(av2[i], lr, ps);
  }
  ps += __shfl_xor(ps,1); ps += __shfl_xor(ps,2); ps += __shfl_xor(ps,4);
  float wsf = (sub == 0) ? exp2f(fminf(ps - 6.f, 12.f)) : 0.f;
  float s = wsf;
  v2h a2[4];
  {
    v2h w2 = splat2(wsf);
    #pragma unroll
    for (int i = 0; i < 4; ++i) a2[i] = w2*xs2[i];
  }

  const int e0 = offb[node*NBKT], e1 = offb[node*NBKT + NBKT];
  const int kfull = e0 + ((e1 - e0) & ~7);
  for (int k = e0; k < kfull; k += 8) {
    v2h xv[4][4];
    float p[4];
    #pragma unroll
    for (int j = 0; j < 4; ++j) {
      u32 boff = csr[k + 2*j + sub];
      uint4 v = *reinterpret_cast<const uint4*>(xc + boff);
      xv[j][0]=u2v(v.x); xv[j][1]=u2v(v.y); xv[j][2]=u2v(v.z); xv[j][3]=u2v(v.w);
      float pp = 0.f;
      #pragma unroll
      for (int i = 0; i < 4; ++i) {
        v2h zz = xv[j][i] + xr2[i];
        v2h lr = __builtin_elementwise_max(zz, zz*c02);
        pp = fdot2(av2[i], lr, pp);
      }
      p[j] = pp;
    }
    #pragma unroll
    for (int j = 0; j < 4; ++j) {
      p[j] += __shfl_xor(p[j],1);
      p[j] += __shfl_xor(p[j],2);
      p[j] += __shfl_xor(p[j],4);
    }
    float w[4];
    #pragma unroll
    for (int j = 0; j < 4; ++j) w[j] = exp2f(fminf(p[j] - 6.f, 12.f));
    s += (w[0] + w[1]) + (w[2] + w[3]);
    #pragma unroll
    for (int j = 0; j < 4; ++j) {
      v2h w2 = splat2(w[j]);
      #pragma unroll
      for (int i = 0; i < 4; ++i) a2[i] += w2*xv[j][i];
    }
  }
  for (int k = kfull; k < e1; k += 2) {
    int kk = k + sub;
    bool val = kk < e1;
    u32 boff = csr[val ? kk : e1-1];
    uint4 v = *reinterpret_cast<const uint4*>(xc + boff);
    v2h xv[4] = {u2v(v.x), u2v(v.y), u2v(v.z), u2v(v.w)};
    float pp = 0.f;
    #pragma unroll
    for (int i = 0; i < 4; ++i) {
      v2h zz = xv[i] + xr2[i];
      v2h lr = __builtin_elementwise_max(zz, zz*c02);
      pp = fdot2(av2[i], lr, pp);
    }
    pp += __shfl_xor(pp,1); pp += __shfl_xor(pp,2); pp += __shfl_xor(pp,4);
    float w = val ? exp2f(fminf(pp - 6.f, 12.f)) : 0.f;
    s += w;
    v2h w2 = splat2(w);
    #pragma unroll
    for (int i = 0; i < 4; ++i) a2[i] += w2*xv[i];
  }
  s += __shfl_xor(s, 32);
  #pragma unroll
  for (int i = 0; i < 4; ++i) {
    u32 t = (u32)__shfl_xor((int)v2u(a2[i]), 32);
    a2[i] += u2v(t);
  }
  float inv = 1.f / s;
  if (sub == 0) {
    float4 b0 = *reinterpret_cast<const float4*>(bias + z*256 + co);
    float4 b1 = *reinterpret_cast<const float4*>(bias + z*256 + co + 4);
    float bv[8] = {b0.x,b0.y,b0.z,b0.w,b1.x,b1.y,b1.z,b1.w};
    u32 o[4];
    #pragma unroll
    for (int i = 0; i < 4; ++i) {
      float lo = fmaxf((float)a2[i][0]*inv + bv[2*i],   0.f);
      float hi = fmaxf((float)a2[i][1]*inv + bv[2*i+1], 0.f);
      o[i] = (u32)f2h(lo) | ((u32)f2h(hi) << 16);
    }
    uint4 ov = {o[0], o[1], o[2], o[3]};
    *reinterpret_cast<uint4*>(outp + (size_t)node*256 + co) = ov;
  }
}

// ---------------- GraphConv: aggregate projected P-slice; XCD-relation affinity ----------------
template<int RELU, int F32OUT>
__global__ __launch_bounds__(256) void k_aggp(
    const u16* __restrict__ C, const float* __restrict__ bias,
    const int* __restrict__ offb4, const u32* __restrict__ csr4,
    u16* __restrict__ outb, float* __restrict__ outf)
{
  const int bid = blockIdx.x;
  const int z = (bid & 7) >> 1;
  const int j4 = ((bid >> 3) << 1) | (bid & 1);
  const int node = j4*4 + (threadIdx.x >> 6);
  if (node >= NN) return;
  const int lane = threadIdx.x & 63;
  const int g = lane >> 4, sl = lane & 15;
  const u16* Cp = C + (size_t)z*(size_t)NN*128;
  const char* Cc = (const char*)Cp + sl*8;   // 4 channels (8B) per lane
  const int* offb = offb4 + (size_t)z*(SM+1);
  const u32* csr = csr4 + (size_t)z*EE;
  const int co = sl*4;
  v2h acc0 = splat2(0.f), acc1 = splat2(0.f);
  const int e0 = offb[node*NBKT], e1 = offb[node*NBKT + NBKT];
  const int kfull = e0 + ((e1 - e0) & ~7);
  for (int k = e0; k < kfull; k += 8) {
    #pragma unroll
    for (int j = 0; j < 2; ++j) {
      u32 boff = csr[k + 2*g + j] >> 4;
      uint2 v = *reinterpret_cast<const uint2*>(Cc + boff);
      acc0 += u2v(v.x);
      acc1 += u2v(v.y);
    }
  }
  for (int k = kfull; k < e1; k += 4) {
    int kk = k + g;
    bool val = kk < e1;
    u32 boff = csr[val ? kk : e1-1] >> 4;
    uint2 v = *reinterpret_cast<const uint2*>(Cc + boff);
    acc0 += u2v(val ? v.x : 0u);
    acc1 += u2v(val ? v.y : 0u);
  }
  float a0 = (float)acc0[0], a1 = (float)acc0[1];
  float a2 = (float)acc1[0], a3 = (float)acc1[1];
  a0 += __shfl_xor(a0,16); a1 += __shfl_xor(a1,16);
  a2 += __shfl_xor(a2,16); a3 += __shfl_xor(a3,16);
  a0 += __shfl_xor(a0,32); a1 += __shfl_xor(a1,32);
  a2 += __shfl_xor(a2,32); a3 += __shfl_xor(a3,32);
  if (g == 0) {
    uint2 q = *reinterpret_cast<const uint2*>(Cp + (size_t)node*128 + 64 + co);
    v2h q0 = u2v(q.x), q1 = u2v(q.y);
    float4 bv = *reinterpret_cast<const float4*>(bias + z*64 + co);
    float v0 = a0 + (float)q0[0] + bv.x;
    float v1 = a1 + (float)q0[1] + bv.y;
    float v2 = a2 + (float)q1[0] + bv.z;
    float v3 = a3 + (float)q1[1] + bv.w;
    if (RELU) {
      v0 = fmaxf(v0, 0.f); v1 = fmaxf(v1, 0.f);
      v2 = fmaxf(v2, 0.f); v3 = fmaxf(v3, 0.f);
    }
    if (F32OUT) {
      float4 o = {v0, v1, v2, v3};
      *reinterpret_cast<float4*>(outf + (size_t)node*256 + z*64 + co) = o;
    } else {
      uint2 o;
      o.x = (u32)f2h(v0) | ((u32)f2h(v1) << 16);
      o.y = (u32)f2h(v2) | ((u32)f2h(v3) << 16);
      *reinterpret_cast<uint2*>(outb + ((size_t)z*NN + node)*64 + co) = o;
    }
  }
}

// ---------------- orchestration ----------------
extern "C" void kernel_launch(void* const* d_in, const int* in_sizes, int n_in,
                              void* d_out, int out_size, void* d_ws, size_t ws_size,
                              hipStream_t stream)
{
  const float* x      = (const float*)d_in[0];
  const int*   ei     = (const int*)  d_in[1];
  const float* Wl1    = (const float*)d_in[2];
  const float* Wr1    = (const float*)d_in[3];
  const float* att1   = (const float*)d_in[4];
  const float* b1     = (const float*)d_in[5];
  const float* Wl2    = (const float*)d_in[6];
  const float* Wr2    = (const float*)d_in[7];
  const float* att2   = (const float*)d_in[8];
  const float* b2     = (const float*)d_in[9];
  const float* Wrel3  = (const float*)d_in[10];
  const float* Wroot3 = (const float*)d_in[11];
  const float* b3     = (const float*)d_in[12];
  const float* Wrel4  = (const float*)d_in[13];
  const float* Wroot4 = (const float*)d_in[14];
  const float* b4     = (const float*)d_in[15];
  float* out = (float*)d_out;

  const dim3 thr(256);
  const size_t NB2048 = (size_t)NN*2048;
  const size_t NB256  = (size_t)NN*256;
  const size_t NB128  = (size_t)NN*128;
  const size_t NB64   = (size_t)NN*64;

  u16* XLR = (u16*)d_ws;                          // [NN][2048] (all relations side by side)
  u16* h   = XLR + NB2048;                        // [R][NN][256]
  u16* xbf = h   + NB256*RR;                      // [NN][256]
  u16* W1T = xbf + NB256;                         // [2048][256]
  u16* W2T = W1T + (size_t)RR*512*256;
  u16* W3T = W2T + (size_t)RR*512*256;            // [R][128][256]
  u16* W4T = W3T + (size_t)RR*128*256;            // [R][128][64]
  int* degb = (int*)(W4T + (size_t)RR*128*64);    // [R][NN][4]
  int* offb = degb + (size_t)RR*SM;               // R*(SM+1)
  int* curb = offb + (size_t)RR*(SM+1);           // [R][NN][4]
  u32* csr4 = (u32*)(curb + (size_t)RR*SM);       // R*EE (byte offsets)
  int* bsum = (int*)(csr4 + (size_t)RR*EE);       // R*SB
  u16* C34 = XLR;                                 // [R][NN][128] aliases XLR
  u16* h3b = XLR + NB128*RR;                      // [R][NN][64]  aliases XLR (disjoint)

  // fused prep: kind 0 = cast x, kinds 1-4 = weight transposes, kind 5 = zero degb
  k_prepall<<<dim3(5000,6), thr, 0, stream>>>(x, xbf, Wl1, Wr1, W1T, Wl2, Wr2, W2T,
                                              Wrel3, Wroot3, W3T, Wrel4, Wroot4, W4T, degb);

  // CSR (src-bucketed, parallel 3-phase scan)
  k_countA <<<dim3((RR*EE+255)/256), thr, 0, stream>>>(ei, degb);
  k_scanA  <<<dim3(RR*SB), thr, 0, stream>>>(degb, bsum);
  k_scanB  <<<dim3(RR), dim3(64), 0, stream>>>(bsum, offb);
  k_scanC  <<<dim3(RR*SB), thr, 0, stream>>>(degb, bsum, offb, curb);
  k_scatterM<<<dim3(20000), thr, 0, stream>>>(ei, curb, csr4);

  const dim3 gNode(20000);                        // gat/aggp: XCD-pair relation affinity
  // L1: XLR = xbf @ W1T^T  (fused GEMM, N=2048; XCD-chunked 1-D grid)
  k_mfma<<<dim3(8*20*16), thr, 0, stream>>>(xbf, W1T, NN, 256, XLR, 2048, 0, 0, 0, 16, 1);
  k_gat<<<gNode, thr, 0, stream>>>(XLR, att1, b1, offb, csr4, h);
  // L2: per-z GEMM back into XLR column slices
  k_mfma<<<dim3(8*20*16), thr, 0, stream>>>(h, W2T, NN, 256, XLR, 2048,
                                            (long)NB256, 512*256, 512, 4, 4);
  k_gat<<<gNode, thr, 0, stream>>>(XLR, att2, b2, offb, csr4, h);
  // L3: C34[z] = h[z] @ [Wrel3|Wroot3][z] ; h3 = relu(aggP + Q + b3)
  k_mfma<<<dim3(8*20*4), thr, 0, stream>>>(h, W3T, NN, 256, C34, 128,
                                           (long)NB256, 128*256, (long)NB128, 1, 4);
  k_aggp<1,0><<<gNode, thr, 0, stream>>>(C34, b3, offb, csr4, h3b, nullptr);
  // L4: C34[z] = h3[z] @ [Wrel4|Wroot4][z] ; out[:,z,:] = aggP + Q + b4
  k_mfma<<<dim3(8*20*4), thr, 0, stream>>>(h3b, W4T, NN, 64, C34, 128,
                                           (long)NB64, 128*64, (long)NB128, 1, 4);
  k_aggp<0,1><<<gNode, thr, 0, stream>>>(C34, b4, offb, csr4, nullptr, out);
}

// Round 17
// 484.784 us; speedup vs baseline: 1.3439x; 1.0077x over previous
//
#include <hip/hip_runtime.h>
#include <hip/hip_fp16.h>
#include <math.h>

#define NN   20000
#define EE   320000
#define RR   4
#define NBKT 4
#define BKTW 5000
#define SM   (NBKT*NN)     // 80000 scan elements per relation
#define SB   40            // scan blocks per relation
#define SE   2000          // elements per scan block

typedef unsigned short u16;
typedef unsigned int   u32;
typedef _Float16 half8v __attribute__((ext_vector_type(8)));
typedef _Float16 v2h    __attribute__((ext_vector_type(2)));
typedef __attribute__((ext_vector_type(4))) float f32x4;

static __device__ __forceinline__ u16 f2h(float f){ return __half_as_ushort(__float2half_rn(f)); }
static __device__ __forceinline__ v2h u2v(u32 u){ union{u32 u; v2h v;} c; c.u=u; return c.v; }
static __device__ __forceinline__ u32 v2u(v2h v){ union{u32 u; v2h v;} c; c.v=v; return c.u; }
static __device__ __forceinline__ v2h splat2(float f){ v2h r; r[0]=(_Float16)f; r[1]=(_Float16)f; return r; }
static __device__ __forceinline__ float fdot2(v2h a, v2h b, float c){
  return __builtin_amdgcn_fdot2(a, b, c, false);
}
static __device__ __forceinline__ void gload_lds16(const void* g, void* l){
  __builtin_amdgcn_global_load_lds((const __attribute__((address_space(1))) void*)g,
                                   (__attribute__((address_space(3))) void*)l, 16, 0, 0);
}

// ---------------- CSR build (src-bucketed lists; parallel 3-phase scan) ----------------
__global__ void k_countA(const int* __restrict__ ei, int* __restrict__ degb){
  int i = blockIdx.x*blockDim.x + threadIdx.x;
  if (i < RR*EE) {
    int r = i / EE, e = i % EE;
    int s = ei[(size_t)r*2*EE + e];
    int d = ei[(size_t)r*2*EE + EE + e];
    int b = s / BKTW;
    atomicAdd(&degb[((size_t)r*NN + d)*NBKT + b], 1);
  }
}
// phase A: block sums (160 blocks x 2000 elements)
__global__ __launch_bounds__(256) void k_scanA(const int* __restrict__ degb, int* __restrict__ bsum){
  int r = blockIdx.x / SB, b = blockIdx.x % SB;
  const int* p = degb + (size_t)r*SM + b*SE;
  int t = threadIdx.x;
  int s = 0;
  for (int i = t; i < SE; i += 256) s += p[i];
  s += __shfl_xor(s,1); s += __shfl_xor(s,2); s += __shfl_xor(s,4);
  s += __shfl_xor(s,8); s += __shfl_xor(s,16); s += __shfl_xor(s,32);
  __shared__ int ws[4];
  if ((t & 63) == 0) ws[t >> 6] = s;
  __syncthreads();
  if (t == 0) bsum[blockIdx.x] = ws[0] + ws[1] + ws[2] + ws[3];
}
// phase B: scan the 40 block sums per relation; write total
__global__ void k_scanB(int* __restrict__ bsum, int* __restrict__ off_all){
  int r = blockIdx.x;
  if (threadIdx.x == 0) {
    int run = 0;
    for (int b = 0; b < SB; ++b) {
      int v = bsum[r*SB + b];
      bsum[r*SB + b] = run;
      run += v;
    }
    off_all[(size_t)r*(SM+1) + SM] = run;   // == EE
  }
}
// phase C: per-block exclusive scan + base -> off/cur
__global__ __launch_bounds__(256) void k_scanC(const int* __restrict__ degb, const int* __restrict__ bsum,
                                               int* __restrict__ off_all, int* __restrict__ cur_all){
  int r = blockIdx.x / SB, b = blockIdx.x % SB;
  const int* p = degb + (size_t)r*SM + b*SE;
  int* off = off_all + (size_t)r*(SM+1) + b*SE;
  int* cur = cur_all + (size_t)r*SM + b*SE;
  int t = threadIdx.x;
  int base_i = t*8;                       // threads 0..249 active
  int v[8]; int tot = 0;
  if (base_i < SE) {
    #pragma unroll
    for (int j = 0; j < 8; ++j) { v[j] = p[base_i + j]; tot += v[j]; }
  }
  __shared__ int part[256];
  part[t] = tot;
  __syncthreads();
  for (int d = 1; d < 256; d <<= 1) {
    int u = (t >= d) ? part[t-d] : 0;
    __syncthreads();
    part[t] += u;
    __syncthreads();
  }
  if (base_i < SE) {
    int run = bsum[r*SB + b] + ((t == 0) ? 0 : part[t-1]);
    #pragma unroll
    for (int j = 0; j < 8; ++j) {
      off[base_i + j] = run;
      cur[base_i + j] = run;
      run += v[j];
    }
  }
}
// merged scatter: pass = blockIdx.x/5000 (dst-range passes keep the random 4B writes L2-local).
__global__ void k_scatterM(const int* __restrict__ ei, int* __restrict__ curb, u32* __restrict__ csr4){
  int bid = blockIdx.x;
  int pass = bid / 5000;
  int i = (bid - pass*5000)*256 + threadIdx.x;
  int dlo = pass*5000, dhi = dlo + 5000;
  if (i < RR*EE) {
    int r = i / EE, e = i - r*EE;
    int d = ei[(size_t)r*2*EE + EE + e];
    if (d >= dlo && d < dhi) {
      int s = ei[(size_t)r*2*EE + e];
      int b = s / BKTW;
      int p = atomicAdd(&curb[((size_t)r*NN + d)*NBKT + b], 1);
      csr4[(size_t)r*EE + p] = (u32)s * 4096u;
    }
  }
}

// ---------------- slim prep: cast x + zero degb ----------------
__global__ void k_prepx(const float* __restrict__ x, u16* __restrict__ xbf, int* __restrict__ degb){
  int kind = blockIdx.y;
  int i = blockIdx.x*256 + threadIdx.x;
  if (kind == 0) {
    if (i < NN*256/4) {
      float4 v = reinterpret_cast<const float4*>(x)[i];
      ushort4 b;
      b.x = f2h(v.x); b.y = f2h(v.y); b.z = f2h(v.z); b.w = f2h(v.w);
      reinterpret_cast<ushort4*>(xbf)[i] = b;
    }
  } else {
    if (i < RR*SM) degb[i] = 0;
  }
}

// ---------------- LDS-tiled weight transpose: dst[r][half*N+n][k] = f2h(src[r][k][n]) ----------------
// 64x64 tiles; coalesced f32 reads (over n), coalesced u16 writes (over k). Padded LDS kills
// bank conflicts. Replaces the strided prep_body (stride-1KB scalar reads = 16x line waste).
__global__ __launch_bounds__(256) void k_wtrans(
    const float* __restrict__ A1, const float* __restrict__ B1, u16* __restrict__ D1,
    const float* __restrict__ A2, const float* __restrict__ B2, u16* __restrict__ D2,
    const float* __restrict__ A3, const float* __restrict__ B3, u16* __restrict__ D3,
    const float* __restrict__ A4, const float* __restrict__ B4, u16* __restrict__ D4)
{
  int kind = blockIdx.z;
  int K, N; const float *A, *B; u16* D;
  if (kind == 0)      { K=256; N=256; A=A1; B=B1; D=D1; }
  else if (kind == 1) { K=256; N=256; A=A2; B=B2; D=D2; }
  else if (kind == 2) { K=256; N=64;  A=A3; B=B3; D=D3; }
  else                { K=64;  N=64;  A=A4; B=B4; D=D4; }
  const int tiles_n = N >> 6;
  const int tiles = (K >> 6) * tiles_n;
  const int tile = blockIdx.x;
  if (tile >= tiles) return;
  const int r = blockIdx.y >> 1, half = blockIdx.y & 1;
  const float* S = half ? B : A;
  const int tk = tile / tiles_n, tn = tile % tiles_n;
  __shared__ u16 ts[64][66];
  const int t = threadIdx.x;
  #pragma unroll
  for (int i = 0; i < 16; ++i) {
    int lin = i*256 + t;
    int row = lin >> 6, col = lin & 63;        // row: k-dim, col: n-dim
    ts[row][col] = f2h(S[((size_t)r*K + tk*64 + row)*N + tn*64 + col]);
  }
  __syncthreads();
  #pragma unroll
  for (int i = 0; i < 16; ++i) {
    int lin = i*256 + t;
    int nrow = lin >> 6, kcol = lin & 63;      // output row: n-dim, col: k-dim
    D[((size_t)r*2*N + half*N + tn*64 + nrow)*K + tk*64 + kcol] = ts[kcol][nrow];
  }
}

// ---------------- MFMA GEMM (f16): Cb = A@BT^T; XCD-chunked 1-D grid ----------------
__global__ __launch_bounds__(256) void k_mfma(
    const u16* __restrict__ A, const u16* __restrict__ BT,
    int M, int K, u16* __restrict__ Cb, int ldc,
    long aZ, long btZ, long cZ, int nby, int nz)
{
  constexpr int BM = 128, BN = 128;
  constexpr int FI = 4, FJ = 4;
  constexpr int CH = 20;                 // bx chunk per XCD
  const int bid = blockIdx.x;
  const int xcd = bid & 7;
  const int u   = bid >> 3;
  const int nbz = nby*nz;
  const int byz = u % nbz;
  const int bxi = u / nbz;
  const int bx  = xcd*CH + bxi;
  const int bm  = bx * BM;
  if (bm >= M) return;
  const int by  = byz % nby;
  const int zz  = byz / nby;
  const int bn  = by * BN;
  A  += (size_t)zz*aZ;
  BT += (size_t)zz*btZ;
  Cb += (size_t)zz*cZ;

  __shared__ u16 As[BM*32];
  __shared__ u16 Bs[BN*32];
  const int t = threadIdx.x;
  const int lane = t & 63, wid = t >> 6;
  const int wr = wid >> 1, wc = wid & 1;
  const int lr = lane & 15, lk = lane >> 4;

  f32x4 acc[FI][FJ];
  #pragma unroll
  for (int i = 0; i < FI; ++i)
    #pragma unroll
    for (int j = 0; j < FJ; ++j) acc[i][j] = (f32x4)(0.f);

  const int nk = K >> 5;
  char* AsB = (char*)As;
  char* BsB = (char*)Bs;

  for (int s = 0; s < nk; ++s) {
    const int kk = s << 5;
    #pragma unroll
    for (int i = 0; i < 2; ++i) {
      int c = t + 256*i;
      int row = c >> 2, sub = c & 3;
      int lsub = sub ^ (row & 3);
      int grow = bm + row; if (grow >= M) grow = M - 1;
      gload_lds16(A + (size_t)grow*K + kk + lsub*8, AsB + c*16);
    }
    #pragma unroll
    for (int i = 0; i < 2; ++i) {
      int c = t + 256*i;
      int row = c >> 2, sub = c & 3;
      int lsub = sub ^ (row & 3);
      gload_lds16(BT + (size_t)(bn + row)*K + kk + lsub*8, BsB + c*16);
    }
    __syncthreads();
    half8v a[FI], b[FJ];
    #pragma unroll
    for (int i = 0; i < FI; ++i) {
      int row = wr*64 + i*16 + lr;
      int sub = lk ^ (row & 3);
      a[i] = *reinterpret_cast<half8v*>(AsB + row*64 + sub*16);
    }
    #pragma unroll
    for (int j = 0; j < FJ; ++j) {
      int col = wc*64 + j*16 + lr;
      int sub = lk ^ (col & 3);
      b[j] = *reinterpret_cast<half8v*>(BsB + col*64 + sub*16);
    }
    #pragma unroll
    for (int i = 0; i < FI; ++i)
      #pragma unroll
      for (int j = 0; j < FJ; ++j)
        acc[i][j] = __builtin_amdgcn_mfma_f32_16x16x32_f16(a[i], b[j], acc[i][j], 0, 0, 0);
    __syncthreads();
  }

  #pragma unroll
  for (int i = 0; i < FI; ++i) {
    #pragma unroll
    for (int j = 0; j < FJ; ++j) {
      int col = bn + wc*64 + j*16 + lr;
      #pragma unroll
      for (int q = 0; q < 4; ++q) {
        int row = bm + wr*64 + i*16 + lk*4 + q;
        if (row < M) Cb[(size_t)row*ldc + col] = f2h(acc[i][j][q]);
      }
    }
  }
}

// ---------------- GATv2 attention: XCD-relation affinity ----------------
__global__ __launch_bounds__(256) void k_gat(
    const u16* __restrict__ xlr,
    const float* __restrict__ att, const float* __restrict__ bias,
    const int* __restrict__ offb4, const u32* __restrict__ csr4,
    u16* __restrict__ out)
{
  const int bid = blockIdx.x;
  const int z = (bid & 7) >> 1;                       // XCD pair -> relation
  const int j4 = ((bid >> 3) << 1) | (bid & 1);       // 0..4999 within relation
  const int node = j4*4 + (threadIdx.x >> 6);
  if (node >= NN) return;
  const int lane = threadIdx.x & 63;
  const int sl = lane & 31, sub = lane >> 5;
  const int* offb = offb4 + (size_t)z*(SM+1);
  const u32* csr = csr4 + (size_t)z*EE;
  u16* outp = out + (size_t)z*(size_t)NN*256;

  const int co = sl*8;
  const char* xc = (const char*)xlr + (size_t)z*1024 + co*2;
  const u16* selfrow = xlr + (size_t)z*512 + (size_t)node*2048;
  const v2h c02 = splat2(0.2f);
  const float L2E = 1.4426950408889634f;

  uint4 rx = *reinterpret_cast<const uint4*>(selfrow + 256 + co);
  v2h xr2[4] = {u2v(rx.x), u2v(rx.y), u2v(rx.z), u2v(rx.w)};
  v2h av2[4];
  {
    float4 q0 = *reinterpret_cast<const float4*>(att + z*256 + co);
    float4 q1 = *reinterpret_cast<const float4*>(att + z*256 + co + 4);
    av2[0][0]=(_Float16)(q0.x*L2E); av2[0][1]=(_Float16)(q0.y*L2E);
    av2[1][0]=(_Float16)(q0.z*L2E); av2[1][1]=(_Float16)(q0.w*L2E);
    av2[2][0]=(_Float16)(q1.x*L2E); av2[2][1]=(_Float16)(q1.y*L2E);
    av2[3][0]=(_Float16)(q1.z*L2E); av2[3][1]=(_Float16)(q1.w*L2E);
  }
  uint4 sx = *reinterpret_cast<const uint4*>(selfrow + co);
  v2h xs2[4] = {u2v(sx.x), u2v(sx.y), u2v(sx.z), u2v(sx.w)};
  float ps = 0.f;
  #pragma unroll
  for (int i = 0; i < 4; ++i) {
    v2h zz = xs2[i] + xr2[i];
    v2h lr = __builtin_elementwise_max(zz, zz*c02);
    ps = fdot2(av2[i], lr, ps);
  }
  ps += __shfl_xor(ps,1); ps += __shfl_xor(ps,2); ps += __shfl_xor(ps,4);
  float wsf = (sub == 0) ? exp2f(fminf(ps - 6.f, 12.f)) : 0.f;
  float s = wsf;
  v2h a2[4];
  {
    v2h w2 = splat2(wsf);
    #pragma unroll
    for (int i = 0; i < 4; ++i) a2[i] = w2*xs2[i];
  }

  const int e0 = offb[node*NBKT], e1 = offb[node*NBKT + NBKT];
  const int kfull = e0 + ((e1 - e0) & ~7);
  for (int k = e0; k < kfull; k += 8) {
    v2h xv[4][4];
    float p[4];
    #pragma unroll
    for (int j = 0; j < 4; ++j) {
      u32 boff = csr[k + 2*j + sub];
      uint4 v = *reinterpret_cast<const uint4*>(xc + boff);
      xv[j][0]=u2v(v.x); xv[j][1]=u2v(v.y); xv[j][2]=u2v(v.z); xv[j][3]=u2v(v.w);
      float pp = 0.f;
      #pragma unroll
      for (int i = 0; i < 4; ++i) {
        v2h zz = xv[j][i] + xr2[i];
        v2h lr = __builtin_elementwise_max(zz, zz*c02);
        pp = fdot2(av2[i], lr, pp);
      }
      p[j] = pp;
    }
    #pragma unroll
    for (int j = 0; j < 4; ++j) {
      p[j] += __shfl_xor(p[j],1);
      p[j] += __shfl_xor(p[j],2);
      p[j] += __shfl_xor(p[j],4);
    }
    float w[4];
    #pragma unroll
    for (int j = 0; j < 4; ++j) w[j] = exp2f(fminf(p[j] - 6.f, 12.f));
    s += (w[0] + w[1]) + (w[2] + w[3]);
    #pragma unroll
    for (int j = 0; j < 4; ++j) {
      v2h w2 = splat2(w[j]);
      #pragma unroll
      for (int i = 0; i < 4; ++i) a2[i] += w2*xv[j][i];
    }
  }
  for (int k = kfull; k < e1; k += 2) {
    int kk = k + sub;
    bool val = kk < e1;
    u32 boff = csr[val ? kk : e1-1];
    uint4 v = *reinterpret_cast<const uint4*>(xc + boff);
    v2h xv[4] = {u2v(v.x), u2v(v.y), u2v(v.z), u2v(v.w)};
    float pp = 0.f;
    #pragma unroll
    for (int i = 0; i < 4; ++i) {
      v2h zz = xv[i] + xr2[i];
      v2h lr = __builtin_elementwise_max(zz, zz*c02);
      pp = fdot2(av2[i], lr, pp);
    }
    pp += __shfl_xor(pp,1); pp += __shfl_xor(pp,2); pp += __shfl_xor(pp,4);
    float w = val ? exp2f(fminf(pp - 6.f, 12.f)) : 0.f;
    s += w;
    v2h w2 = splat2(w);
    #pragma unroll
    for (int i = 0; i < 4; ++i) a2[i] += w2*xv[i];
  }
  s += __shfl_xor(s, 32);
  #pragma unroll
  for (int i = 0; i < 4; ++i) {
    u32 t = (u32)__shfl_xor((int)v2u(a2[i]), 32);
    a2[i] += u2v(t);
  }
  float inv = 1.f / s;
  if (sub == 0) {
    float4 b0 = *reinterpret_cast<const float4*>(bias + z*256 + co);
    float4 b1 = *reinterpret_cast<const float4*>(bias + z*256 + co + 4);
    float bv[8] = {b0.x,b0.y,b0.z,b0.w,b1.x,b1.y,b1.z,b1.w};
    u32 o[4];
    #pragma unroll
    for (int i = 0; i < 4; ++i) {
      float lo = fmaxf((float)a2[i][0]*inv + bv[2*i],   0.f);
      float hi = fmaxf((float)a2[i][1]*inv + bv[2*i+1], 0.f);
      o[i] = (u32)f2h(lo) | ((u32)f2h(hi) << 16);
    }
    uint4 ov = {o[0], o[1], o[2], o[3]};
    *reinterpret_cast<uint4*>(outp + (size_t)node*256 + co) = ov;
  }
}

// ---------------- GraphConv: aggregate projected P-slice; XCD-relation affinity ----------------
template<int RELU, int F32OUT>
__global__ __launch_bounds__(256) void k_aggp(
    const u16* __restrict__ C, const float* __restrict__ bias,
    const int* __restrict__ offb4, const u32* __restrict__ csr4,
    u16* __restrict__ outb, float* __restrict__ outf)
{
  const int bid = blockIdx.x;
  const int z = (bid & 7) >> 1;
  const int j4 = ((bid >> 3) << 1) | (bid & 1);
  const int node = j4*4 + (threadIdx.x >> 6);
  if (node >= NN) return;
  const int lane = threadIdx.x & 63;
  const int g = lane >> 4, sl = lane & 15;
  const u16* Cp = C + (size_t)z*(size_t)NN*128;
  const char* Cc = (const char*)Cp + sl*8;
  const int* offb = offb4 + (size_t)z*(SM+1);
  const u32* csr = csr4 + (size_t)z*EE;
  const int co = sl*4;
  v2h acc0 = splat2(0.f), acc1 = splat2(0.f);
  const int e0 = offb[node*NBKT], e1 = offb[node*NBKT + NBKT];
  const int kfull = e0 + ((e1 - e0) & ~7);
  for (int k = e0; k < kfull; k += 8) {
    #pragma unroll
    for (int j = 0; j < 2; ++j) {
      u32 boff = csr[k + 2*g + j] >> 4;
      uint2 v = *reinterpret_cast<const uint2*>(Cc + boff);
      acc0 += u2v(v.x);
      acc1 += u2v(v.y);
    }
  }
  for (int k = kfull; k < e1; k += 4) {
    int kk = k + g;
    bool val = kk < e1;
    u32 boff = csr[val ? kk : e1-1] >> 4;
    uint2 v = *reinterpret_cast<const uint2*>(Cc + boff);
    acc0 += u2v(val ? v.x : 0u);
    acc1 += u2v(val ? v.y : 0u);
  }
  float a0 = (float)acc0[0], a1 = (float)acc0[1];
  float a2 = (float)acc1[0], a3 = (float)acc1[1];
  a0 += __shfl_xor(a0,16); a1 += __shfl_xor(a1,16);
  a2 += __shfl_xor(a2,16); a3 += __shfl_xor(a3,16);
  a0 += __shfl_xor(a0,32); a1 += __shfl_xor(a1,32);
  a2 += __shfl_xor(a2,32); a3 += __shfl_xor(a3,32);
  if (g == 0) {
    uint2 q = *reinterpret_cast<const uint2*>(Cp + (size_t)node*128 + 64 + co);
    v2h q0 = u2v(q.x), q1 = u2v(q.y);
    float4 bv = *reinterpret_cast<const float4*>(bias + z*64 + co);
    float v0 = a0 + (float)q0[0] + bv.x;
    float v1 = a1 + (float)q0[1] + bv.y;
    float v2 = a2 + (float)q1[0] + bv.z;
    float v3 = a3 + (float)q1[1] + bv.w;
    if (RELU) {
      v0 = fmaxf(v0, 0.f); v1 = fmaxf(v1, 0.f);
      v2 = fmaxf(v2, 0.f); v3 = fmaxf(v3, 0.f);
    }
    if (F32OUT) {
      float4 o = {v0, v1, v2, v3};
      *reinterpret_cast<float4*>(outf + (size_t)node*256 + z*64 + co) = o;
    } else {
      uint2 o;
      o.x = (u32)f2h(v0) | ((u32)f2h(v1) << 16);
      o.y = (u32)f2h(v2) | ((u32)f2h(v3) << 16);
      *reinterpret_cast<uint2*>(outb + ((size_t)z*NN + node)*64 + co) = o;
    }
  }
}

// ---------------- orchestration ----------------
extern "C" void kernel_launch(void* const* d_in, const int* in_sizes, int n_in,
                              void* d_out, int out_size, void* d_ws, size_t ws_size,
                              hipStream_t stream)
{
  const float* x      = (const float*)d_in[0];
  const int*   ei     = (const int*)  d_in[1];
  const float* Wl1    = (const float*)d_in[2];
  const float* Wr1    = (const float*)d_in[3];
  const float* att1   = (const float*)d_in[4];
  const float* b1     = (const float*)d_in[5];
  const float* Wl2    = (const float*)d_in[6];
  const float* Wr2    = (const float*)d_in[7];
  const float* att2   = (const float*)d_in[8];
  const float* b2     = (const float*)d_in[9];
  const float* Wrel3  = (const float*)d_in[10];
  const float* Wroot3 = (const float*)d_in[11];
  const float* b3     = (const float*)d_in[12];
  const float* Wrel4  = (const float*)d_in[13];
  const float* Wroot4 = (const float*)d_in[14];
  const float* b4     = (const float*)d_in[15];
  float* out = (float*)d_out;

  const dim3 thr(256);
  const size_t NB2048 = (size_t)NN*2048;
  const size_t NB256  = (size_t)NN*256;
  const size_t NB128  = (size_t)NN*128;
  const size_t NB64   = (size_t)NN*64;

  u16* XLR = (u16*)d_ws;                          // [NN][2048]
  u16* h   = XLR + NB2048;                        // [R][NN][256]
  u16* xbf = h   + NB256*RR;                      // [NN][256]
  u16* W1T = xbf + NB256;                         // [2048][256]
  u16* W2T = W1T + (size_t)RR*512*256;
  u16* W3T = W2T + (size_t)RR*512*256;            // [R][128][256]
  u16* W4T = W3T + (size_t)RR*128*256;            // [R][128][64]
  int* degb = (int*)(W4T + (size_t)RR*128*64);    // [R][NN][4]
  int* offb = degb + (size_t)RR*SM;               // R*(SM+1)
  int* curb = offb + (size_t)RR*(SM+1);           // [R][NN][4]
  u32* csr4 = (u32*)(curb + (size_t)RR*SM);       // R*EE (byte offsets)
  int* bsum = (int*)(csr4 + (size_t)RR*EE);       // R*SB
  u16* C34 = XLR;                                 // [R][NN][128] aliases XLR
  u16* h3b = XLR + NB128*RR;                      // [R][NN][64]  aliases XLR (disjoint)

  // prep: cast x + zero degb (slim) and LDS-tiled weight transposes (coalesced)
  k_prepx <<<dim3(5000,2), thr, 0, stream>>>(x, xbf, degb);
  k_wtrans<<<dim3(16,8,4), thr, 0, stream>>>(Wl1, Wr1, W1T, Wl2, Wr2, W2T,
                                             Wrel3, Wroot3, W3T, Wrel4, Wroot4, W4T);

  // CSR (src-bucketed, parallel 3-phase scan)
  k_countA <<<dim3((RR*EE+255)/256), thr, 0, stream>>>(ei, degb);
  k_scanA  <<<dim3(RR*SB), thr, 0, stream>>>(degb, bsum);
  k_scanB  <<<dim3(RR), dim3(64), 0, stream>>>(bsum, offb);
  k_scanC  <<<dim3(RR*SB), thr, 0, stream>>>(degb, bsum, offb, curb);
  k_scatterM<<<dim3(20000), thr, 0, stream>>>(ei, curb, csr4);

  const dim3 gNode(20000);
  // L1: XLR = xbf @ W1T^T  (fused GEMM, N=2048; XCD-chunked 1-D grid)
  k_mfma<<<dim3(8*20*16), thr, 0, stream>>>(xbf, W1T, NN, 256, XLR, 2048, 0, 0, 0, 16, 1);
  k_gat<<<gNode, thr, 0, stream>>>(XLR, att1, b1, offb, csr4, h);
  // L2: per-z GEMM back into XLR column slices
  k_mfma<<<dim3(8*20*16), thr, 0, stream>>>(h, W2T, NN, 256, XLR, 2048,
                                            (long)NB256, 512*256, 512, 4, 4);
  k_gat<<<gNode, thr, 0, stream>>>(XLR, att2, b2, offb, csr4, h);
  // L3: C34[z] = h[z] @ [Wrel3|Wroot3][z] ; h3 = relu(aggP + Q + b3)
  k_mfma<<<dim3(8*20*4), thr, 0, stream>>>(h, W3T, NN, 256, C34, 128,
                                           (long)NB256, 128*256, (long)NB128, 1, 4);
  k_aggp<1,0><<<gNode, thr, 0, stream>>>(C34, b3, offb, csr4, h3b, nullptr);
  // L4: C34[z] = h3[z] @ [Wrel4|Wroot4][z] ; out[:,z,:] = aggP + Q + b4
  k_mfma<<<dim3(8*20*4), thr, 0, stream>>>(h3b, W4T, NN, 64, C34, 128,
                                           (long)NB64, 128*64, (long)NB128, 1, 4);
  k_aggp<0,1><<<gNode, thr, 0, stream>>>(C34, b4, offb, csr4, nullptr, out);
}